// Round 3
// baseline (262.035 us; speedup 1.0000x reference)
//
#include <hip/hip_runtime.h>

#define BB 16
#define TT 2048
#define NROW 513
#define HOP 256
#define OUTLB 524288          // out length per batch
#define FTO 28                // output frames per block
#define SPAN (FTO*HOP)        // 7168
#define TILES 74              // ceil(2048/28)
#define RZ 513                // z row stride in complex (odd => frame bank spread)

__device__ __forceinline__ int brev9(int k){ return (int)(__brev((unsigned)k)>>23); }
__device__ __forceinline__ int zidx(int f,int m){ return f*RZ + (m ^ ((m>>4)&28) ^ (f<<2)); }

__global__ __launch_bounds__(512,4) void istft_fused(
    const float* __restrict__ sr, const float* __restrict__ si,
    float* __restrict__ out)
{
  __shared__ float2 zc[8*RZ];                       // 32832 B
  __shared__ __align__(16) float2 ola[SPAN/2];      // 28672 B
  __shared__ float2 ttab[256];                      // 2048 B  => 63552 B total

  const int tid  = threadIdx.x;
  const int b    = blockIdx.x / TILES;
  const int tile = blockIdx.x % TILES;
  const int L0   = tile*SPAN + 384;                 // y-index of span start
  const int Tbase= tile*FTO - 2;

  if (tid < 256) {                                  // W^j = e^{+2pi i j/512}
    float s,c; __sincosf((float)tid*0.012271846303085130f,&s,&c);
    ttab[tid]=make_float2(c,s);
  }
  for (int i=tid;i<SPAN/2;i+=512) ola[i]=make_float2(0.f,0.f);

  const int f  = tid & 7;                           // frame slot within chunk
  const int pp = tid >> 3;                          // [0,64)
  const float* srb = sr + (size_t)b*NROW*TT;
  const float* sib = si + (size_t)b*NROW*TT;

  // per-thread constant pack twiddles e^{i*pi*k/512} for k = cc*64+pp
  float ctw[4], stw[4];
  #pragma unroll
  for (int cc=0;cc<4;++cc){
    __sincosf((float)(cc*64+pp)*0.006135923151542565f,&stw[cc],&ctw[cc]);
  }

  // ---- helpers ----
  auto storeZ = [&](int cc, float ar,float ai,float br,float bi,float cr,float ci){
    int k = cc*64+pp;
    if (k==0){
      zc[zidx(f,0)] = make_float2(0.5f*(ar+br), 0.5f*(ar-br));
      zc[zidx(f,1)] = make_float2(cr, -ci);         // brev9(256)=1, Z=conj(X[256])
    } else {
      float Er=0.5f*(ar+br), Ei=0.5f*(ai-bi);
      float Dr=0.5f*(ar-br), Di=0.5f*(ai+bi);
      float Or=Dr*ctw[cc]-Di*stw[cc], Oi=Dr*stw[cc]+Di*ctw[cc];
      zc[zidx(f,brev9(k))]     = make_float2(Er-Oi, Ei+Or);
      zc[zidx(f,brev9(512-k))] = make_float2(Er+Oi, Or-Ei);
    }
  };

  auto do_fft = [&](){
    #pragma unroll
    for (int st=0; st<4; ++st){                     // 4 radix-4 stages
      __syncthreads();
      const int h = 1<<(2*st);
      #pragma unroll
      for (int i=0;i<2;++i){
        int q   = pp + 64*i;                        // [0,128)
        int ilo = q & (h-1);
        int base= ((q>>(2*st))<<(2*st+2)) + ilo;
        float2 w1 = ttab[ilo<<(8-2*st)];
        float2 w2 = ttab[ilo<<(7-2*st)];
        float2 e0=zc[zidx(f,base)],     e1=zc[zidx(f,base+h)];
        float2 e2=zc[zidx(f,base+2*h)], e3=zc[zidx(f,base+3*h)];
        float t1r=e1.x*w1.x-e1.y*w1.y, t1i=e1.x*w1.y+e1.y*w1.x;
        float t3r=e3.x*w1.x-e3.y*w1.y, t3i=e3.x*w1.y+e3.y*w1.x;
        float arr=e0.x+t1r, ari=e0.y+t1i, brr=e0.x-t1r, bri=e0.y-t1i;
        float crr=e2.x+t3r, cri=e2.y+t3i, drr=e2.x-t3r, dri=e2.y-t3i;
        float cwr=crr*w2.x-cri*w2.y, cwi=crr*w2.y+cri*w2.x;
        float dwr=drr*w2.x-dri*w2.y, dwi=drr*w2.y+dri*w2.x;
        zc[zidx(f,base)]     = make_float2(arr+cwr, ari+cwi);
        zc[zidx(f,base+2*h)] = make_float2(arr-cwr, ari-cwi);
        zc[zidx(f,base+h)]   = make_float2(brr-dwi, bri+dwr);  // W^128=+i
        zc[zidx(f,base+3*h)] = make_float2(brr+dwi, bri-dwr);
      }
    }
    __syncthreads();
    #pragma unroll
    for (int i=0;i<4;++i){                          // final radix-2, h=256
      int q = pp + 64*i;                            // [0,256)
      float2 tw = ttab[q];
      float2 u = zc[zidx(f,q)], v = zc[zidx(f,q+256)];
      float tr=v.x*tw.x-v.y*tw.y, ti=v.x*tw.y+v.y*tw.x;
      zc[zidx(f,q)]     = make_float2(u.x+tr, u.y+ti);
      zc[zidx(f,q+256)] = make_float2(u.x-tr, u.y-ti);
    }
  };

  auto do_ola = [&](int chunkT){
    #pragma unroll
    for (int g=0; g<4; ++g){                        // frames g, g+4 disjoint
      __syncthreads();
      int slot = g + 4*(tid>>8);
      int tg   = chunkT + slot;
      int offB = tg*HOP - L0;
      bool vt  = (tg>=0 && tg<TT);
      int mbq  = tid & 255;
      #pragma unroll
      for (int i=0;i<2;++i){
        int m = mbq + 256*i;
        float2 v = zc[zidx(slot,m)];
        int j0 = 2*m;
        float w0 = 0.5f-0.5f*__cosf((float)j0    *0.006135923151542565f);
        float w1v= 0.5f-0.5f*__cosf((float)(j0+1)*0.006135923151542565f);
        int idx = offB + j0;
        if (vt && idx>=0 && idx<SPAN){
          float2 o = ola[idx>>1];
          o.x += v.x*(1.f/512.f)*w0;
          o.y += v.y*(1.f/512.f)*w1v;
          ola[idx>>1] = o;
        }
      }
    }
  };

  // ---- main: 2 chunk-pairs; pair loads issued back-to-back (full 64B lines) ----
  for (int half=0; half<2; ++half){
    const int c0  = 2*half;
    const int ta  = Tbase + 8*c0 + f;
    const int tb_ = ta + 8;
    const int tca = min(max(ta ,0),TT-1);
    const int tcb = min(max(tb_,0),TT-1);
    const float ma  = (ta >=0 && ta <TT)?1.f:0.f;
    const float mb2 = (tb_>=0 && tb_<TT)?1.f:0.f;

    float sAr[4],sAi[4],sBr[4],sBi[4];              // stash for chunk c0+1
    float sCr=0.f, sCi=0.f;

    __syncthreads();                                // zc WAR vs prev phase-3
    #pragma unroll
    for (int cc=0;cc<4;++cc){
      int k = cc*64+pp;                             // [0,256)
      const float* pr  = srb + (size_t)k*TT;
      const float* pi_ = sib + (size_t)k*TT;
      const float* qr  = srb + (size_t)(512-k)*TT;
      const float* qi  = sib + (size_t)(512-k)*TT;
      float ar0=pr [tca], ar1=pr [tcb];             // adjacent halves of one line
      float ai0=pi_[tca], ai1=pi_[tcb];
      float br0=qr [tca], br1=qr [tcb];
      float bi0=qi [tca], bi1=qi [tcb];
      sAr[cc]=ar1; sAi[cc]=ai1; sBr[cc]=br1; sBi[cc]=bi1;
      float cr0=0.f, ci0=0.f;
      if (cc==0 && pp==0){                          // k==0 thread: X[256] too
        const float* rr = srb + (size_t)256*TT;
        const float* ri = sib + (size_t)256*TT;
        cr0 = rr[tca]; sCr = rr[tcb];
        ci0 = ri[tca]; sCi = ri[tcb];
      }
      storeZ(cc, ar0*ma, ai0*ma, br0*ma, bi0*ma, cr0*ma, ci0*ma);
    }
    do_fft();
    do_ola(Tbase + 8*c0);

    __syncthreads();                                // zc WAR
    #pragma unroll
    for (int cc=0;cc<4;++cc){
      storeZ(cc, sAr[cc]*mb2, sAi[cc]*mb2, sBr[cc]*mb2, sBi[cc]*mb2, sCr*mb2, sCi*mb2);
    }
    do_fft();
    do_ola(Tbase + 8*(c0+1));
  }
  __syncthreads();

  // ---- finalize: divide by window^2 envelope (1.5 interior), store ----
  const bool edge = (tile==0)|(tile==TILES-1);
  float* outb = out + (size_t)b*OUTLB;
  #pragma unroll
  for (int i=0;i<4;++i){
    int i4 = tid + 512*i;                           // float4 index in span
    if (i4 < SPAN/4){
      int s  = 4*i4;
      int gs = tile*SPAN + s;
      if (gs < OUTLB){
        float4 v = ((const float4*)ola)[i4];
        float r[4]={v.x,v.y,v.z,v.w};
        if (!edge){
          #pragma unroll
          for(int e=0;e<4;++e) r[e] *= (2.f/3.f);   // Hann 4x OLA env = 1.5
        } else {
          #pragma unroll
          for(int e=0;e<4;++e){
            int l = L0 + s + e;
            int j0 = l & 255, tb = l >> 8;
            float env=0.f;
            #pragma unroll
            for (int mm=0;mm<4;++mm){
              int t2 = tb-mm;
              if (t2>=0 && t2<TT){
                float wv = 0.5f-0.5f*__cosf((float)(j0+256*mm)*0.006135923151542565f);
                env += wv*wv;
              }
            }
            r[e] /= env;
          }
        }
        *(float4*)(outb+gs) = make_float4(r[0],r[1],r[2],r[3]);
      }
    }
  }
}

extern "C" void kernel_launch(void* const* d_in, const int* in_sizes, int n_in,
                              void* d_out, int out_size, void* d_ws, size_t ws_size,
                              hipStream_t stream) {
  const float* sr = (const float*)d_in[0];
  const float* si = (const float*)d_in[1];
  float* out = (float*)d_out;
  istft_fused<<<BB*TILES, 512, 0, stream>>>(sr, si, out);
}

// Round 4
// 253.021 us; speedup vs baseline: 1.0356x; 1.0356x over previous
//
#include <hip/hip_runtime.h>

#define BB 16
#define TT 2048
#define NROW 513
#define HOP 256
#define OUTLB 524288          // out length per batch
#define FTO 28                // output frames per block
#define SPAN (FTO*HOP)        // 7168
#define TILES 74              // ceil(2048/28)
#define RZ 513                // z row stride in complex (odd => frame bank spread)

__device__ __forceinline__ int brev9(int k){ return (int)(__brev((unsigned)k)>>23); }
__device__ __forceinline__ int zidx(int f,int m){ return f*RZ + (m ^ ((m>>4)&28) ^ (f<<2)); }

__global__ __launch_bounds__(512,2) void istft_fused(
    const float* __restrict__ sr, const float* __restrict__ si,
    const float* __restrict__ win, float* __restrict__ out)
{
  __shared__ float2 zc[8*RZ];                       // 32832 B
  __shared__ __align__(16) float2 ola[SPAN/2];      // 28672 B
  __shared__ float2 ttab[256];                      // 2048 B
  __shared__ float2 wtab[512];                      // 4096 B  => 67648 B total

  const int tid  = threadIdx.x;
  const int b    = blockIdx.x / TILES;
  const int tile = blockIdx.x % TILES;
  const int L0   = tile*SPAN + 384;                 // y-index of span start
  const int Tbase= tile*FTO - 2;

  if (tid < 256) {                                  // W^j = e^{+2pi i j/512}
    float s,c; __sincosf((float)tid*0.012271846303085130f,&s,&c);
    ttab[tid]=make_float2(c,s);
  }
  { // window/512 table as float2 pairs (conflict-free stride-1 b64 reads)
    float2 wv = ((const float2*)win)[tid];
    wtab[tid] = make_float2(wv.x*(1.f/512.f), wv.y*(1.f/512.f));
  }
  for (int i=tid;i<SPAN/2;i+=512) ola[i]=make_float2(0.f,0.f);

  const int f  = tid & 7;                           // frame slot within chunk
  const int pp = tid >> 3;                          // [0,64)
  const float* srb = sr + (size_t)b*NROW*TT;
  const float* sib = si + (size_t)b*NROW*TT;

  // pack twiddles e^{i*pi*k/512} for k = cc*64+pp
  float ctw[4], stw[4];
  #pragma unroll
  for (int cc=0;cc<4;++cc){
    __sincosf((float)(cc*64+pp)*0.006135923151542565f,&stw[cc],&ctw[cc]);
  }

  auto storeZ = [&](int cc, float ar,float ai,float br,float bi,float cr,float ci){
    int k = cc*64+pp;
    if (k==0){
      zc[zidx(f,0)] = make_float2(0.5f*(ar+br), 0.5f*(ar-br));
      zc[zidx(f,1)] = make_float2(cr, -ci);         // brev9(256)=1, Z=conj(X[256])
    } else {
      float Er=0.5f*(ar+br), Ei=0.5f*(ai-bi);
      float Dr=0.5f*(ar-br), Di=0.5f*(ai+bi);
      float Or=Dr*ctw[cc]-Di*stw[cc], Oi=Dr*stw[cc]+Di*ctw[cc];
      zc[zidx(f,brev9(k))]     = make_float2(Er-Oi, Ei+Or);
      zc[zidx(f,brev9(512-k))] = make_float2(Er+Oi, Or-Ei);
    }
  };

  auto do_fft = [&](){
    #pragma unroll
    for (int st=0; st<4; ++st){                     // 4 radix-4 stages
      __syncthreads();
      const int h = 1<<(2*st);
      #pragma unroll
      for (int i=0;i<2;++i){
        int q   = pp + 64*i;                        // [0,128)
        int ilo = q & (h-1);
        int base= ((q>>(2*st))<<(2*st+2)) + ilo;
        float2 w1 = ttab[ilo<<(8-2*st)];
        float2 w2 = ttab[ilo<<(7-2*st)];
        float2 e0=zc[zidx(f,base)],     e1=zc[zidx(f,base+h)];
        float2 e2=zc[zidx(f,base+2*h)], e3=zc[zidx(f,base+3*h)];
        float t1r=e1.x*w1.x-e1.y*w1.y, t1i=e1.x*w1.y+e1.y*w1.x;
        float t3r=e3.x*w1.x-e3.y*w1.y, t3i=e3.x*w1.y+e3.y*w1.x;
        float arr=e0.x+t1r, ari=e0.y+t1i, brr=e0.x-t1r, bri=e0.y-t1i;
        float crr=e2.x+t3r, cri=e2.y+t3i, drr=e2.x-t3r, dri=e2.y-t3i;
        float cwr=crr*w2.x-cri*w2.y, cwi=crr*w2.y+cri*w2.x;
        float dwr=drr*w2.x-dri*w2.y, dwi=drr*w2.y+dri*w2.x;
        zc[zidx(f,base)]     = make_float2(arr+cwr, ari+cwi);
        zc[zidx(f,base+2*h)] = make_float2(arr-cwr, ari-cwi);
        zc[zidx(f,base+h)]   = make_float2(brr-dwi, bri+dwr);  // W^128=+i
        zc[zidx(f,base+3*h)] = make_float2(brr+dwi, bri-dwr);
      }
    }
    __syncthreads();
    #pragma unroll
    for (int i=0;i<4;++i){                          // final radix-2, h=256
      int q = pp + 64*i;                            // [0,256)
      float2 tw = ttab[q];
      float2 u = zc[zidx(f,q)], v = zc[zidx(f,q+256)];
      float tr=v.x*tw.x-v.y*tw.y, ti=v.x*tw.y+v.y*tw.x;
      zc[zidx(f,q)]     = make_float2(u.x+tr, u.y+ti);
      zc[zidx(f,q+256)] = make_float2(u.x-tr, u.y-ti);
    }
  };

  auto do_ola = [&](int chunkT){
    #pragma unroll
    for (int g=0; g<4; ++g){                        // frames g, g+4 disjoint
      __syncthreads();
      int slot = g + 4*(tid>>8);
      int tg   = chunkT + slot;
      int offB = tg*HOP - L0;
      bool vt  = (tg>=0 && tg<TT);
      int mbq  = tid & 255;
      #pragma unroll
      for (int i=0;i<2;++i){
        int m = mbq + 256*i;
        float2 v = zc[zidx(slot,m)];
        float2 w = wtab[m];                         // (w[2m],w[2m+1])/512
        int idx = offB + 2*m;
        if (vt && idx>=0 && idx<SPAN){
          float2 o = ola[idx>>1];
          o.x += v.x*w.x;
          o.y += v.y*w.y;
          ola[idx>>1] = o;
        }
      }
    }
  };

  // ---- main: 2 chunk-pairs; pair loads issued back-to-back (full 64B lines) ----
  for (int half=0; half<2; ++half){
    const int c0  = 2*half;
    const int ta  = Tbase + 8*c0 + f;
    const int tb_ = ta + 8;
    const int tca = min(max(ta ,0),TT-1);
    const int tcb = min(max(tb_,0),TT-1);
    const float ma  = (ta >=0 && ta <TT)?1.f:0.f;
    const float mb2 = (tb_>=0 && tb_<TT)?1.f:0.f;

    float sAr[4],sAi[4],sBr[4],sBi[4];              // stash for chunk c0+1
    float sCr=0.f, sCi=0.f;

    __syncthreads();                                // zc WAR vs prev phase-3
    #pragma unroll
    for (int cc=0;cc<4;++cc){
      int k = cc*64+pp;                             // [0,256)
      const float* pr  = srb + (size_t)k*TT;
      const float* pi_ = sib + (size_t)k*TT;
      const float* qr  = srb + (size_t)(512-k)*TT;
      const float* qi  = sib + (size_t)(512-k)*TT;
      float ar0=pr [tca], ar1=pr [tcb];             // adjacent halves of one line
      float ai0=pi_[tca], ai1=pi_[tcb];
      float br0=qr [tca], br1=qr [tcb];
      float bi0=qi [tca], bi1=qi [tcb];
      sAr[cc]=ar1; sAi[cc]=ai1; sBr[cc]=br1; sBi[cc]=bi1;
      float cr0=0.f, ci0=0.f;
      if (cc==0 && pp==0){                          // k==0 thread: X[256] too
        const float* rr = srb + (size_t)256*TT;
        const float* ri = sib + (size_t)256*TT;
        cr0 = rr[tca]; sCr = rr[tcb];
        ci0 = ri[tca]; sCi = ri[tcb];
      }
      storeZ(cc, ar0*ma, ai0*ma, br0*ma, bi0*ma, cr0*ma, ci0*ma);
    }
    do_fft();
    do_ola(Tbase + 8*c0);

    __syncthreads();                                // zc WAR
    #pragma unroll
    for (int cc=0;cc<4;++cc){
      storeZ(cc, sAr[cc]*mb2, sAi[cc]*mb2, sBr[cc]*mb2, sBi[cc]*mb2, sCr*mb2, sCi*mb2);
    }
    do_fft();
    do_ola(Tbase + 8*(c0+1));
  }
  __syncthreads();

  // ---- finalize: divide by window^2 envelope (1.5 interior), store ----
  const bool edge = (tile==0)|(tile==TILES-1);
  float* outb = out + (size_t)b*OUTLB;
  #pragma unroll
  for (int i=0;i<4;++i){
    int i4 = tid + 512*i;                           // float4 index in span
    if (i4 < SPAN/4){
      int s  = 4*i4;
      int gs = tile*SPAN + s;
      if (gs < OUTLB){
        float4 v = ((const float4*)ola)[i4];
        float r[4]={v.x,v.y,v.z,v.w};
        if (!edge){
          #pragma unroll
          for(int e=0;e<4;++e) r[e] *= (2.f/3.f);   // Hann 4x OLA env = 1.5
        } else {
          #pragma unroll
          for(int e=0;e<4;++e){
            int l = L0 + s + e;
            int j0 = l & 255, tb = l >> 8;
            float env=0.f;
            #pragma unroll
            for (int mm=0;mm<4;++mm){
              int t2 = tb-mm;
              if (t2>=0 && t2<TT){
                float wv = 0.5f-0.5f*__cosf((float)(j0+256*mm)*0.006135923151542565f);
                env += wv*wv;
              }
            }
            r[e] /= env;
          }
        }
        *(float4*)(outb+gs) = make_float4(r[0],r[1],r[2],r[3]);
      }
    }
  }
}

extern "C" void kernel_launch(void* const* d_in, const int* in_sizes, int n_in,
                              void* d_out, int out_size, void* d_ws, size_t ws_size,
                              hipStream_t stream) {
  const float* sr = (const float*)d_in[0];
  const float* si = (const float*)d_in[1];
  const float* w  = (const float*)d_in[2];
  float* out = (float*)d_out;
  istft_fused<<<BB*TILES, 512, 0, stream>>>(sr, si, w, out);
}

// Round 5
// 248.049 us; speedup vs baseline: 1.0564x; 1.0200x over previous
//
#include <hip/hip_runtime.h>

#define BB 16
#define TT 2048
#define NROW 513
#define HOP 256
#define OUTLB 524288          // out length per batch
#define FTO 28                // output frames per block
#define SPAN (FTO*HOP)        // 7168
#define TILES 74              // ceil(2048/28)
#define RZ 513                // z row stride in complex

__device__ __forceinline__ int brev9(int k){ return (int)(__brev((unsigned)k)>>23); }
__device__ __forceinline__ int zidx(int f,int m){ return f*RZ + (m ^ ((m>>4)&28) ^ (f<<2)); }

__global__ __launch_bounds__(512,4) void istft_fused(
    const float* __restrict__ sr, const float* __restrict__ si,
    const float* __restrict__ win, float* __restrict__ out)
{
  __shared__ float2 zc[8*RZ];                       // 32832 B
  __shared__ float2 ttab[256];                      // 2048 B
  __shared__ float2 wtab[512];                      // 4096 B => 38976 B total

  const int tid  = threadIdx.x;
  const int b    = blockIdx.x / TILES;
  const int tile = blockIdx.x % TILES;
  const int Tbase= tile*FTO - 2;

  if (tid < 256){                                   // W^j = e^{+2pi i j/512}
    float s,c; __sincosf((float)tid*0.012271846303085130f,&s,&c);
    ttab[tid]=make_float2(c,s);
  }
  wtab[tid] = ((const float2*)win)[tid];            // (w[2m], w[2m+1])

  float2 acc[7];                                    // 7 output pairs per thread
  #pragma unroll
  for (int i=0;i<7;++i) acc[i]=make_float2(0.f,0.f);

  const int f  = tid & 7;                           // frame slot within chunk
  const int pp = tid >> 3;                          // [0,64)
  const float* srb = sr + (size_t)b*NROW*TT;
  const float* sib = si + (size_t)b*NROW*TT;

  // pack twiddles e^{i*pi*k/512} for k = cc*64+pp
  float ctw[4], stw[4];
  #pragma unroll
  for (int cc=0;cc<4;++cc){
    __sincosf((float)(cc*64+pp)*0.006135923151542565f,&stw[cc],&ctw[cc]);
  }

  auto storeZ = [&](int cc, float ar,float ai,float br,float bi,float cr,float ci){
    int k = cc*64+pp;
    if (k==0){
      zc[zidx(f,0)] = make_float2(0.5f*(ar+br), 0.5f*(ar-br));
      zc[zidx(f,1)] = make_float2(cr, -ci);         // brev9(256)=1, Z=conj(X[256])
    } else {
      float Er=0.5f*(ar+br), Ei=0.5f*(ai-bi);
      float Dr=0.5f*(ar-br), Di=0.5f*(ai+bi);
      float Or=Dr*ctw[cc]-Di*stw[cc], Oi=Dr*stw[cc]+Di*ctw[cc];
      zc[zidx(f,brev9(k))]     = make_float2(Er-Oi, Ei+Or);
      zc[zidx(f,brev9(512-k))] = make_float2(Er+Oi, Or-Ei);
    }
  };

  auto do_fft = [&](){
    #pragma unroll
    for (int st=0; st<4; ++st){                     // 4 radix-4 stages
      __syncthreads();
      const int h = 1<<(2*st);
      #pragma unroll
      for (int i=0;i<2;++i){
        int q   = pp + 64*i;                        // [0,128)
        int ilo = q & (h-1);
        int base= ((q>>(2*st))<<(2*st+2)) + ilo;
        float2 w1 = ttab[ilo<<(8-2*st)];
        float2 w2 = ttab[ilo<<(7-2*st)];
        float2 e0=zc[zidx(f,base)],     e1=zc[zidx(f,base+h)];
        float2 e2=zc[zidx(f,base+2*h)], e3=zc[zidx(f,base+3*h)];
        float t1r=e1.x*w1.x-e1.y*w1.y, t1i=e1.x*w1.y+e1.y*w1.x;
        float t3r=e3.x*w1.x-e3.y*w1.y, t3i=e3.x*w1.y+e3.y*w1.x;
        float arr=e0.x+t1r, ari=e0.y+t1i, brr=e0.x-t1r, bri=e0.y-t1i;
        float crr=e2.x+t3r, cri=e2.y+t3i, drr=e2.x-t3r, dri=e2.y-t3i;
        float cwr=crr*w2.x-cri*w2.y, cwi=crr*w2.y+cri*w2.x;
        float dwr=drr*w2.x-dri*w2.y, dwi=drr*w2.y+dri*w2.x;
        zc[zidx(f,base)]     = make_float2(arr+cwr, ari+cwi);
        zc[zidx(f,base+2*h)] = make_float2(arr-cwr, ari-cwi);
        zc[zidx(f,base+h)]   = make_float2(brr-dwi, bri+dwr);  // W^128=+i
        zc[zidx(f,base+3*h)] = make_float2(brr+dwi, bri-dwr);
      }
    }
    __syncthreads();
    #pragma unroll
    for (int i=0;i<4;++i){                          // final radix-2, h=256
      int q = pp + 64*i;                            // [0,256)
      float2 tw = ttab[q];
      float2 u = zc[zidx(f,q)], v = zc[zidx(f,q+256)];
      float tr=v.x*tw.x-v.y*tw.y, ti=v.x*tw.y+v.y*tw.x;
      zc[zidx(f,q)]     = make_float2(u.x+tr, u.y+ti);
      zc[zidx(f,q+256)] = make_float2(u.x-tr, u.y-ti);
    }
  };

  // register-gather OLA: thread owns pairs p0 = 2*(tid+512i); contributions
  // from slots s with j0-256s in [0,1024), j0 = p0 + 896 - 2048c (masked
  // frames are zero in zc, so no validity checks needed)
  auto do_gather = [&](int c){
    __syncthreads();
    const int jb = 896 - 2048*c;
    #pragma unroll
    for (int i=0;i<7;++i){
      int j0 = 2*(tid + 512*i) + jb;                // even
      int s_lo = max(0, (j0-768)>>8);
      int s_hi = min(7, j0>>8);
      for (int s=s_lo; s<=s_hi; ++s){
        int m0 = (j0 - 256*s)>>1;                   // [0,512), even j0 => exact
        float2 v = zc[zidx(s,m0)];
        float2 w = wtab[m0];
        acc[i].x += v.x*w.x;
        acc[i].y += v.y*w.y;
      }
    }
  };

  // ---- main: 2 chunk-pairs; pair loads issued back-to-back (full 64B lines) ----
  for (int half=0; half<2; ++half){
    const int c0  = 2*half;
    const int ta  = Tbase + 8*c0 + f;
    const int tb_ = ta + 8;
    const int tca = min(max(ta ,0),TT-1);
    const int tcb = min(max(tb_,0),TT-1);
    const float ma  = (ta >=0 && ta <TT)?(1.f/512.f):0.f;   // fold 1/512 scale
    const float mb2 = (tb_>=0 && tb_<TT)?(1.f/512.f):0.f;

    float sAr[4],sAi[4],sBr[4],sBi[4];              // stash for chunk c0+1
    float sCr=0.f, sCi=0.f;

    __syncthreads();                                // zc WAR vs prev gather
    #pragma unroll
    for (int cc=0;cc<4;++cc){
      int k = cc*64+pp;                             // [0,256)
      const float* pr  = srb + (size_t)k*TT;
      const float* pi_ = sib + (size_t)k*TT;
      const float* qr  = srb + (size_t)(512-k)*TT;
      const float* qi  = sib + (size_t)(512-k)*TT;
      float ar0=pr [tca], ar1=pr [tcb];             // adjacent halves of one line
      float ai0=pi_[tca], ai1=pi_[tcb];
      float br0=qr [tca], br1=qr [tcb];
      float bi0=qi [tca], bi1=qi [tcb];
      sAr[cc]=ar1; sAi[cc]=ai1; sBr[cc]=br1; sBi[cc]=bi1;
      float cr0=0.f, ci0=0.f;
      if (cc==0 && pp==0){                          // k==0 thread: X[256] too
        const float* rr = srb + (size_t)256*TT;
        const float* ri = sib + (size_t)256*TT;
        cr0 = rr[tca]; sCr = rr[tcb];
        ci0 = ri[tca]; sCi = ri[tcb];
      }
      storeZ(cc, ar0*ma, ai0*ma, br0*ma, bi0*ma, cr0*ma, ci0*ma);
    }
    do_fft();
    do_gather(c0);

    __syncthreads();                                // zc WAR
    #pragma unroll
    for (int cc=0;cc<4;++cc){
      storeZ(cc, sAr[cc]*mb2, sAi[cc]*mb2, sBr[cc]*mb2, sBi[cc]*mb2, sCr*mb2, sCi*mb2);
    }
    do_fft();
    do_gather(c0+1);
  }

  // ---- finalize from registers: env division (1.5 interior), float2 store ----
  const bool edge = (tile==0)|(tile==TILES-1);
  float* outb = out + (size_t)b*OUTLB;
  const int gbase = tile*SPAN;
  #pragma unroll
  for (int i=0;i<7;++i){
    int p0 = 2*(tid + 512*i);
    int gs = gbase + p0;
    if (gs < OUTLB){
      float2 r = acc[i];
      if (!edge){
        r.x *= (2.f/3.f); r.y *= (2.f/3.f);         // Hann 4x OLA env = 1.5
      } else {
        #pragma unroll
        for (int e=0;e<2;++e){
          int l = gbase + 384 + p0 + e;
          int j0 = l & 255, tb = l >> 8;
          float env=0.f;
          #pragma unroll
          for (int mm=0;mm<4;++mm){
            int t2 = tb-mm;
            if (t2>=0 && t2<TT){
              float wv = 0.5f-0.5f*__cosf((float)(j0+256*mm)*0.006135923151542565f);
              env += wv*wv;
            }
          }
          ((float*)&r)[e] /= env;
        }
      }
      *(float2*)(outb+gs) = r;
    }
  }
}

extern "C" void kernel_launch(void* const* d_in, const int* in_sizes, int n_in,
                              void* d_out, int out_size, void* d_ws, size_t ws_size,
                              hipStream_t stream) {
  const float* sr = (const float*)d_in[0];
  const float* si = (const float*)d_in[1];
  const float* w  = (const float*)d_in[2];
  float* out = (float*)d_out;
  istft_fused<<<BB*TILES, 512, 0, stream>>>(sr, si, w, out);
}